// Round 21
// baseline (136.479 us; speedup 1.0000x reference)
//
#include <hip/hip_runtime.h>
#include <math.h>

#define NN 10000
#define NE 160000

typedef __attribute__((ext_vector_type(8))) short s8v;
typedef __attribute__((ext_vector_type(4))) float f4v;
typedef unsigned short u16;

// ---- ws byte layout ----
#define OFF_P1HB 0u          // N*32 bf16      = 640000 B
#define OFF_P3HB 640000u     // N*3*32 bf16    = 1920000 B
#define OFF_WB   2560000u    // NWB u16        = 143360 B
#define OFF_SCR  2703360u    // 8320 f32 scratch (T1t,T3t,bt1,bt3) = 33280 B
#define OFF_P1N  2736640u    // N*32 f32       = 1280000 B
#define OFF_P3N  4016640u    // N*3*32 f32     = 3840000 B

// ---- wb (u16) offsets: fused weights, lane-consumption order [..][64][8] --
#define OWF1  0       // [b8][nt6][ks2][64][8] = 49152  (Wf1 = W1@W2@W3)
#define OBB1  49152   // [nt6][64][8]          = 3072   (bf1, k<8 else 0)
#define OII1T 52224   // [nt2][64][8]          = 1024
#define OWF3  53248   // [b8][nt2][ks2][64][8] = 16384  (Wf3 = W13@W23@W33)
#define OBB3  69632   // [nt2][64][8]          = 1024   (bf3)
#define OII3T 70656   // [nt2][64][8]          = 1024
#define NWB   71680

__device__ __forceinline__ short f2b(float f) {
    unsigned u = __float_as_uint(f);
    u += 0x7fffu + ((u >> 16) & 1u);
    return (short)(u >> 16);
}
__device__ __forceinline__ float tanhf_fast(float x) {
    float xc = fminf(9.f, fmaxf(-9.f, x));
    float e = __expf(2.f * xc);
    return (e - 1.f) * __builtin_amdgcn_rcpf(e + 1.f);
}

// ---------------- node prep: p1h/p3h = tanh(x@W+b) -> bf16 ----------------
__global__ __launch_bounds__(256) void node_prep(
    const float* __restrict__ p1, const float* __restrict__ p3,
    const float* __restrict__ pp1_W, const float* __restrict__ pp1_b,
    const float* __restrict__ pp3_W, const float* __restrict__ pp3_b,
    u16* __restrict__ p1hb, u16* __restrict__ p3hb)
{
    __shared__ float Ws[2][32 * 32];
    __shared__ float bsm[2][32];
    int tid = threadIdx.x;
    for (int i = tid; i < 32 * 32; i += 256) { Ws[0][i] = pp1_W[i]; Ws[1][i] = pp3_W[i]; }
    if (tid < 32) { bsm[0][tid] = pp1_b[tid]; bsm[1][tid] = pp3_b[tid]; }
    __syncthreads();
    int idx = blockIdx.x * 256 + tid;
    int n = idx >> 7;
    int r = (idx >> 5) & 3;
    int c = idx & 31;
    int sel = (r == 0) ? 0 : 1;
    const float* in = (r == 0) ? (p1 + n * 32) : (p3 + (n * 3 + (r - 1)) * 32);
    float acc = bsm[sel][c];
    #pragma unroll
    for (int k = 0; k < 32; ++k) acc += in[k] * Ws[sel][k * 32 + c];
    short v = f2b(tanhf(acc));
    if (r == 0) p1hb[n * 32 + c] = (u16)v;
    else        p3hb[(n * 3 + (r - 1)) * 32 + c] = (u16)v;
}

// ---- wprep stage 1 (4-lane cooperative), TRANSPOSED outputs:
//      T1t[q][k] = (W1@W2)[k][q]  (96x64),  T3t[q][k] = (W13@W23)[k][q] (32x64)
//      bt1 = b1@W2 + b2 [96], bt3 = b13@W23 + b23 [32] -----------------------
__global__ __launch_bounds__(256) void wprep1(
    const float* __restrict__ W1, const float* __restrict__ W2,
    const float* __restrict__ b1, const float* __restrict__ b2,
    const float* __restrict__ W13, const float* __restrict__ W23,
    const float* __restrict__ b13, const float* __restrict__ b23,
    float* __restrict__ scr)
{
    int gt = blockIdx.x * 256 + threadIdx.x;     // 33280 threads
    int i0 = gt >> 2, sub = gt & 3;
    if (i0 >= 8320) return;
    int i = i0;
    float a = 0.f;
    int k0 = sub * 8;
    if (i < 6144) {                       // T1t: q = i>>6, k = i&63
        int q = i >> 6, k = i & 63;
        #pragma unroll
        for (int c = k0; c < k0 + 8; ++c) a += W1[k * 32 + c] * W2[c * 96 + q];
    } else if ((i -= 6144) < 2048) {      // T3t: q = i>>6, k = i&63
        int q = i >> 6, k = i & 63;
        #pragma unroll
        for (int c = k0; c < k0 + 8; ++c) a += W13[k * 32 + c] * W23[c * 32 + q];
    } else if ((i -= 2048) < 96) {
        if (sub == 0) a = b2[i];
        #pragma unroll
        for (int c = k0; c < k0 + 8; ++c) a += b1[c] * W2[c * 96 + i];
    } else {
        i -= 96;
        if (sub == 0) a = b23[i];
        #pragma unroll
        for (int c = k0; c < k0 + 8; ++c) a += b13[c] * W23[c * 32 + i];
    }
    a += __shfl_xor(a, 1);
    a += __shfl_xor(a, 2);
    if (sub == 0) scr[i0] = a;
}

// ---- wprep stage 2 (4-lane cooperative): fused bf16 tables.
// T1t/T3t transposed layout -> 8 consecutive threads (j=0..7 -> k
// consecutive) read scr[q*64+k] as one coalesced 32B group; W3 operand is a
// broadcast across them. ~8x fewer L1 requests than round 20. ---------------
__global__ __launch_bounds__(256) void wprep2(
    const float* __restrict__ W3, const float* __restrict__ W33,
    const float* __restrict__ ii1, const float* __restrict__ ii3,
    const float* __restrict__ scr, u16* __restrict__ wb)
{
    int gt = blockIdx.x * 256 + threadIdx.x;     // 286720 threads = 4*NWB
    int i0 = gt >> 2, sub = gt & 3;
    int i = i0;
    float a = 0.f;
    if (i < 49152) {            // WF1[b][nt][ks][L][j] = Wf1[k][c*8+b], K=96
        int b = i / 6144, r = i % 6144;
        int nt = r / 1024, r2 = r % 1024;
        int ks = r2 / 512, r3 = r2 & 511;
        int L = r3 >> 3, j = r3 & 7;
        int k = ks * 32 + (L >> 4) * 8 + j;
        int c = 16 * nt + (L & 15);
        int q0 = sub * 24;
        #pragma unroll 8
        for (int q = q0; q < q0 + 24; ++q)
            a += scr[q * 64 + k] * W3[q * 768 + c * 8 + b];
    } else if ((i -= 49152) < 3072) {   // BB1[nt][L][j], K=96
        int nt = i / 512, r3 = i & 511;
        int L = r3 >> 3, j = r3 & 7;
        if ((L >> 4) == 0) {
            int x = (16 * nt + (L & 15)) * 8 + j;
            int q0 = sub * 24;
            #pragma unroll 8
            for (int q = q0; q < q0 + 24; ++q)
                a += scr[8192 + q] * W3[q * 768 + x];
        }
    } else if ((i -= 3072) < 1024) {    // II1T[nt][L][j]  (copy)
        if (sub == 0) {
            int nt = i / 512, r3 = i & 511;
            int L = r3 >> 3, j = r3 & 7;
            a = ii1[((L >> 4) * 8 + j) * 32 + 16 * nt + (L & 15)];
        }
    } else if ((i -= 1024) < 16384) {   // WF3[b][nt][ks][L][j], K=32
        int b = i / 2048, r = i % 2048;
        int nt = r / 1024, r2 = r % 1024;
        int ks = r2 / 512, r3 = r2 & 511;
        int L = r3 >> 3, j = r3 & 7;
        int k = ks * 32 + (L >> 4) * 8 + j;
        int c = 16 * nt + (L & 15);
        int q0 = sub * 8;
        #pragma unroll
        for (int q = q0; q < q0 + 8; ++q)
            a += scr[6144 + q * 64 + k] * W33[q * 256 + c * 8 + b];
    } else if ((i -= 16384) < 1024) {   // BB3[nt][L][j], K=32
        int nt = i / 512, r3 = i & 511;
        int L = r3 >> 3, j = r3 & 7;
        if ((L >> 4) == 0) {
            int x = (16 * nt + (L & 15)) * 8 + j;
            int q0 = sub * 8;
            #pragma unroll
            for (int q = q0; q < q0 + 8; ++q)
                a += scr[8288 + q] * W33[q * 256 + x];
        }
    } else {                            // II3T[nt][L][j]  (copy)
        if (sub == 0) {
            i -= 1024;
            int nt = i / 512, r3 = i & 511;
            int L = r3 >> 3, j = r3 & 7;
            a = ii3[((L >> 4) * 8 + j) * 32 + 16 * nt + (L & 15)];
        }
    }
    a += __shfl_xor(a, 1);
    a += __shfl_xor(a, 2);
    if (sub == 0) wb[i0] = (u16)f2b(a);
}

// ------- fused edge kernel: 32 edges per 1-wave block (2 M-tiles) ---------
// Round-15/19/20 edge kernel EXACTLY ((64,3): empirical VGPR cap ~85 fits
// the 80-VGPR wave program; (64,4) caps at 64 -> spills). Measured ~107 us.
__global__ __launch_bounds__(64, 3) void edge_kernel(
    const u16* __restrict__ p1hb, const u16* __restrict__ p3hb,
    const float* __restrict__ r3, const float* __restrict__ basis,
    const int* __restrict__ idx_i, const int* __restrict__ idx_j,
    const u16* __restrict__ wb,
    const float* __restrict__ ii1b, const float* __restrict__ ii3b,
    float* __restrict__ p1n, float* __restrict__ p3n)
{
    // 3 KB LDS, single wave per block
    __shared__ int4 smem4[192];
    char* sw = (char*)smem4;
    int*   sIdxI = (int*)(sw + 0);       // [32]
    int*   sIdxJ = (int*)(sw + 128);     // [32]
    float* sBasT = (float*)(sw + 256);   // [8][32] transposed basis
    float* sR3   = (float*)(sw + 1280);  // [3][32]
    u16*   sT2   = (u16*)(sw + 1664);    // [16][40] transpose buffer

    const int l   = threadIdx.x & 63;
    const int r16 = l & 15;
    const int kg  = l >> 4;
    const int ebase = blockIdx.x * 32;

    // ---- staging (single wave: in-order LDS, no barriers) ----
    if (l < 32) sIdxI[l] = idx_i[ebase + l];
    else        sIdxJ[l - 32] = idx_j[ebase + l - 32];
    {
        int e = l & 31, hf = l >> 5;
        const float4* bp = (const float4*)(basis + (size_t)(ebase + e) * 8);
        float4 q = bp[hf];
        sBasT[(4 * hf + 0) * 32 + e] = q.x;
        sBasT[(4 * hf + 1) * 32 + e] = q.y;
        sBasT[(4 * hf + 2) * 32 + e] = q.z;
        sBasT[(4 * hf + 3) * 32 + e] = q.w;
        if (hf == 0) {
            sR3[e]      = r3[(size_t)(ebase + e) * 3 + 0];
            sR3[32 + e] = r3[(size_t)(ebase + e) * 3 + 1];
            sR3[64 + e] = r3[(size_t)(ebase + e) * 3 + 2];
        }
    }

    const float vii1[2] = { ii1b[r16], ii1b[16 + r16] };
    const float vii3[2] = { ii3b[r16], ii3b[16 + r16] };

    const f4v zf = {0.f, 0.f, 0.f, 0.f};

    // basis as K=8-padded A-fragment (for bias-init MFMAs)
    s8v bA[2];
    #pragma unroll
    for (int m = 0; m < 2; ++m) {
        s8v t;
        #pragma unroll
        for (int j = 0; j < 8; ++j)
            t[j] = (kg == 0) ? f2b(sBasT[j * 32 + m * 16 + r16]) : (short)0;
        bA[m] = t;
    }

    // ---- pi1: inter gathers (A-frags) ----
    s8v avI[2], avJ[2];
    #pragma unroll
    for (int m = 0; m < 2; ++m) {
        int rowA = m * 16 + r16;
        avI[m] = *(const s8v*)(p1hb + (size_t)sIdxI[rowA] * 32 + kg * 8);
        avJ[m] = *(const s8v*)(p1hb + (size_t)sIdxJ[rowA] * 32 + kg * 8);
    }

    // accT init = basis @ bf1  (bias term)
    f4v accT[2][6];
    {
        const u16* gBB = wb + OBB1;
        #pragma unroll
        for (int nt = 0; nt < 6; ++nt) {
            s8v bbv = *(const s8v*)(gBB + (nt * 64 + l) * 8);
            #pragma unroll
            for (int m = 0; m < 2; ++m)
                accT[m][nt] = __builtin_amdgcn_mfma_f32_16x16x32_bf16(bA[m], bbv, zf, 0, 0, 0);
        }
    }

    // ---- pi1 main: accT += basis_b * (inter @ Wf1_b) ----
    {
        const u16* gW = wb + OWF1;
        #pragma unroll 2
        for (int b = 0; b < 8; ++b) {
            float tb[2][4];
            #pragma unroll
            for (int m = 0; m < 2; ++m)
                #pragma unroll
                for (int rr = 0; rr < 4; ++rr)
                    tb[m][rr] = sBasT[b * 32 + m * 16 + 4 * kg + rr];
            #pragma unroll
            for (int nt = 0; nt < 6; ++nt) {
                const u16* bp = gW + ((size_t)(b * 6 + nt) * 2) * 512 + l * 8;
                s8v bv0 = *(const s8v*)(bp);
                s8v bv1 = *(const s8v*)(bp + 512);
                #pragma unroll
                for (int m = 0; m < 2; ++m) {
                    f4v D = __builtin_amdgcn_mfma_f32_16x16x32_bf16(avI[m], bv0, zf, 0, 0, 0);
                    D = __builtin_amdgcn_mfma_f32_16x16x32_bf16(avJ[m], bv1, D, 0, 0, 0);
                    #pragma unroll
                    for (int rr = 0; rr < 4; ++rr)
                        accT[m][nt][rr] += tb[m][rr] * D[rr];
                }
            }
        }
    }

    // ---- ii1: tanh(i1_1 @ ii1_W + b) -> atomic p1n[idx_j] ----
    {
        const u16* gII = wb + OII1T;
        #pragma unroll
        for (int m = 0; m < 2; ++m) {
            #pragma unroll
            for (int nt = 0; nt < 2; ++nt)
                #pragma unroll
                for (int rr = 0; rr < 4; ++rr)
                    sT2[(4 * kg + rr) * 40 + 16 * nt + r16] = (u16)f2b(accT[m][nt][rr]);
            s8v av = *(const s8v*)(sT2 + r16 * 40 + 8 * kg);
            #pragma unroll
            for (int nt = 0; nt < 2; ++nt) {
                s8v bv = *(const s8v*)(gII + (nt * 64 + l) * 8);
                f4v ia = __builtin_amdgcn_mfma_f32_16x16x32_bf16(av, bv, zf, 0, 0, 0);
                #pragma unroll
                for (int rr = 0; rr < 4; ++rr) {
                    int rowD = m * 16 + 4 * kg + rr;
                    atomicAdd(&p1n[(size_t)sIdxJ[rowD] * 32 + 16 * nt + r16],
                              tanhf_fast(ia[rr] + vii1[nt]));
                }
            }
        }
    }

    // ---- pi3 branch per Cartesian d ----
    const u16* gW3  = wb + OWF3;
    const u16* gBB3 = wb + OBB3;
    const u16* gII3 = wb + OII3T;
    for (int d = 0; d < 3; ++d) {
        s8v avI3[2], avJ3[2];
        #pragma unroll
        for (int m = 0; m < 2; ++m) {
            int rowA = m * 16 + r16;
            avI3[m] = *(const s8v*)(p3hb + ((size_t)sIdxI[rowA] * 3 + d) * 32 + kg * 8);
            avJ3[m] = *(const s8v*)(p3hb + ((size_t)sIdxJ[rowA] * 3 + d) * 32 + kg * 8);
        }
        f4v accP[2][2];
        #pragma unroll
        for (int nt = 0; nt < 2; ++nt) {
            s8v bbv = *(const s8v*)(gBB3 + (nt * 64 + l) * 8);
            #pragma unroll
            for (int m = 0; m < 2; ++m)
                accP[m][nt] = __builtin_amdgcn_mfma_f32_16x16x32_bf16(bA[m], bbv, zf, 0, 0, 0);
        }
        #pragma unroll 2
        for (int b = 0; b < 8; ++b) {
            float tb[2][4];
            #pragma unroll
            for (int m = 0; m < 2; ++m)
                #pragma unroll
                for (int rr = 0; rr < 4; ++rr)
                    tb[m][rr] = sBasT[b * 32 + m * 16 + 4 * kg + rr];
            #pragma unroll
            for (int nt = 0; nt < 2; ++nt) {
                const u16* bp = gW3 + ((size_t)(b * 2 + nt) * 2) * 512 + l * 8;
                s8v bv0 = *(const s8v*)(bp);
                s8v bv1 = *(const s8v*)(bp + 512);
                #pragma unroll
                for (int m = 0; m < 2; ++m) {
                    f4v D = __builtin_amdgcn_mfma_f32_16x16x32_bf16(avI3[m], bv0, zf, 0, 0, 0);
                    D = __builtin_amdgcn_mfma_f32_16x16x32_bf16(avJ3[m], bv1, D, 0, 0, 0);
                    #pragma unroll
                    for (int rr = 0; rr < 4; ++rr)
                        accP[m][nt][rr] += tb[m][rr] * D[rr];
                }
            }
        }
        // ii3 + combine + atomic p3n
        #pragma unroll
        for (int m = 0; m < 2; ++m) {
            #pragma unroll
            for (int nt = 0; nt < 2; ++nt)
                #pragma unroll
                for (int rr = 0; rr < 4; ++rr)
                    sT2[(4 * kg + rr) * 40 + 16 * nt + r16] = (u16)f2b(accP[m][nt][rr]);
            s8v av = *(const s8v*)(sT2 + r16 * 40 + 8 * kg);
            #pragma unroll
            for (int nt = 0; nt < 2; ++nt) {
                s8v bv = *(const s8v*)(gII3 + (nt * 64 + l) * 8);
                f4v ja = __builtin_amdgcn_mfma_f32_16x16x32_bf16(av, bv, zf, 0, 0, 0);
                #pragma unroll
                for (int rr = 0; rr < 4; ++rr) {
                    int rowD = m * 16 + 4 * kg + rr;
                    float i3a = tanhf_fast(ja[rr] + vii3[nt]);
                    float val = i3a * accT[m][2 + nt][rr] + sR3[d * 32 + rowD] * accT[m][4 + nt][rr];
                    atomicAdd(&p3n[((size_t)sIdxJ[rowD] * 3 + d) * 32 + 16 * nt + r16], val);
                }
            }
        }
    }
}

// ---------------- finalize: p1o = sum_d p3n^2 + p1n ; p3o = p3n * p1o -----
__global__ __launch_bounds__(256) void finalize_kernel(
    const float* __restrict__ p1n, const float* __restrict__ p3n,
    float* __restrict__ out)
{
    int t = blockIdx.x * 256 + threadIdx.x;
    int n = t >> 5, c = t & 31;
    float a0 = p3n[(n * 3 + 0) * 32 + c];
    float a1 = p3n[(n * 3 + 1) * 32 + c];
    float a2 = p3n[(n * 3 + 2) * 32 + c];
    float p1o = p1n[t] + a0 * a0 + a1 * a1 + a2 * a2;
    out[t] = p1o;
    float* o3 = out + NN * 32;
    o3[(n * 3 + 0) * 32 + c] = a0 * p1o;
    o3[(n * 3 + 1) * 32 + c] = a1 * p1o;
    o3[(n * 3 + 2) * 32 + c] = a2 * p1o;
}

extern "C" void kernel_launch(void* const* d_in, const int* in_sizes, int n_in,
                              void* d_out, int out_size, void* d_ws, size_t ws_size,
                              hipStream_t stream) {
    const float* p1     = (const float*)d_in[0];
    const float* p3     = (const float*)d_in[1];
    const float* r3     = (const float*)d_in[2];
    const float* basis  = (const float*)d_in[3];
    const int*   idx_i  = (const int*)d_in[4];
    const int*   idx_j  = (const int*)d_in[5];
    const float* pp1_W  = (const float*)d_in[6];
    const float* pp1_b  = (const float*)d_in[7];
    const float* pi1_W1 = (const float*)d_in[8];
    const float* pi1_b1 = (const float*)d_in[9];
    const float* pi1_W2 = (const float*)d_in[10];
    const float* pi1_b2 = (const float*)d_in[11];
    const float* pi1_W3 = (const float*)d_in[12];
    const float* ii1_W  = (const float*)d_in[13];
    const float* ii1_b  = (const float*)d_in[14];
    const float* pp3_W  = (const float*)d_in[15];
    const float* pp3_b  = (const float*)d_in[16];
    const float* pi3_W1 = (const float*)d_in[17];
    const float* pi3_b1 = (const float*)d_in[18];
    const float* pi3_W2 = (const float*)d_in[19];
    const float* pi3_b2 = (const float*)d_in[20];
    const float* pi3_W3 = (const float*)d_in[21];
    const float* ii3_W  = (const float*)d_in[22];
    const float* ii3_b  = (const float*)d_in[23];

    char* ws = (char*)d_ws;
    u16*   p1hb = (u16*)(ws + OFF_P1HB);
    u16*   p3hb = (u16*)(ws + OFF_P3HB);
    u16*   wb   = (u16*)(ws + OFF_WB);
    float* scr  = (float*)(ws + OFF_SCR);
    float* p1n  = (float*)(ws + OFF_P1N);
    float* p3n  = (float*)(ws + OFF_P3N);

    hipMemsetAsync(p1n, 0, 5120000, stream);

    node_prep<<<dim3(5000), dim3(256), 0, stream>>>(p1, p3, pp1_W, pp1_b, pp3_W, pp3_b, p1hb, p3hb);
    wprep1<<<dim3(130), dim3(256), 0, stream>>>(
        pi1_W1, pi1_W2, pi1_b1, pi1_b2, pi3_W1, pi3_W2, pi3_b1, pi3_b2, scr);
    wprep2<<<dim3(1120), dim3(256), 0, stream>>>(
        pi1_W3, pi3_W3, ii1_W, ii3_W, scr, wb);

    edge_kernel<<<dim3(NE / 32), dim3(64), 0, stream>>>(
        p1hb, p3hb, r3, basis, idx_i, idx_j, wb,
        ii1_b, ii3_b, p1n, p3n);

    finalize_kernel<<<dim3(1250), dim3(256), 0, stream>>>(p1n, p3n, (float*)d_out);
}

// Round 22
// 133.094 us; speedup vs baseline: 1.0254x; 1.0254x over previous
//
#include <hip/hip_runtime.h>
#include <math.h>

#define NN 10000
#define NE 160000

typedef __attribute__((ext_vector_type(8))) short s8v;
typedef __attribute__((ext_vector_type(4))) float f4v;
typedef unsigned short u16;

// ---- ws byte layout ----
#define OFF_P1HB 0u          // N*32 bf16      = 640000 B
#define OFF_P3HB 640000u     // N*3*32 bf16    = 1920000 B
#define OFF_WB   2560000u    // NWB u16        = 143360 B
#define OFF_P1N  2736640u    // N*32 f32       = 1280000 B
#define OFF_P3N  4016640u    // N*3*32 f32     = 3840000 B (contiguous after p1n)

// ---- wb (u16) offsets: fused weights, lane-consumption order [..][64][8] --
#define OWF1  0       // [b8][nt6][ks2][64][8] = 49152  (Wf1 = W1@W2@W3)
#define OBB1  49152   // [nt6][64][8]          = 3072   (bf1 folded, kg==0 else 0)
#define OII1T 52224   // [nt2][64][8]          = 1024
#define OWF3  53248   // [b8][nt2][ks2][64][8] = 16384  (Wf3 = W13@W23@W33)
#define OBB3  69632   // [nt2][64][8]          = 1024   (bf3 folded)
#define OII3T 70656   // [nt2][64][8]          = 1024
#define NWB   71680

__device__ __forceinline__ short f2b(float f) {
    unsigned u = __float_as_uint(f);
    u += 0x7fffu + ((u >> 16) & 1u);
    return (short)(u >> 16);
}
__device__ __forceinline__ float tanhf_fast(float x) {
    float xc = fminf(9.f, fmaxf(-9.f, x));
    float e = __expf(2.f * xc);
    return (e - 1.f) * __builtin_amdgcn_rcpf(e + 1.f);
}

// ============ single prep kernel: node_prep | weight fusion | zero-init ====
// blocks [0,5000): node_prep; [5000,5064): pi1 fuse (12 cols each);
// [5064,5096): pi3 fuse (8 cols each); 5096: II copies; [5097,6347): zero.
__global__ __launch_bounds__(256) void prep_kernel(
    const float* __restrict__ p1, const float* __restrict__ p3,
    const float* __restrict__ pp1_W, const float* __restrict__ pp1_b,
    const float* __restrict__ pp3_W, const float* __restrict__ pp3_b,
    const float* __restrict__ W1, const float* __restrict__ W2,
    const float* __restrict__ W3,
    const float* __restrict__ b1v, const float* __restrict__ b2v,
    const float* __restrict__ ii1,
    const float* __restrict__ W13, const float* __restrict__ W23,
    const float* __restrict__ W33,
    const float* __restrict__ b13v, const float* __restrict__ b23v,
    const float* __restrict__ ii3,
    u16* __restrict__ p1hb, u16* __restrict__ p3hb,
    u16* __restrict__ wb, float* __restrict__ p1n)
{
    __shared__ float smem[6912];       // 27648 B, role-dependent
    const int blk = blockIdx.x;
    const int tid = threadIdx.x;

    if (blk < 5000) {
        // ---------------- node_prep ----------------
        float* Ws0 = smem;             // [1024]
        float* Ws1 = smem + 1024;      // [1024]
        float* bs0 = smem + 2048;      // [32]
        float* bs1 = smem + 2080;      // [32]
        for (int i = tid; i < 1024; i += 256) { Ws0[i] = pp1_W[i]; Ws1[i] = pp3_W[i]; }
        if (tid < 32) { bs0[tid] = pp1_b[tid]; bs1[tid] = pp3_b[tid]; }
        __syncthreads();
        int idx = blk * 256 + tid;
        int n = idx >> 7;
        int r = (idx >> 5) & 3;
        int c = idx & 31;
        const float* Ws = (r == 0) ? Ws0 : Ws1;
        const float* bs = (r == 0) ? bs0 : bs1;
        const float* in = (r == 0) ? (p1 + n * 32) : (p3 + (n * 3 + (r - 1)) * 32);
        float acc = bs[c];
        #pragma unroll
        for (int k = 0; k < 32; ++k) acc += in[k] * Ws[k * 32 + c];
        short v = f2b(tanhf(acc));
        if (r == 0) p1hb[n * 32 + c] = (u16)v;
        else        p3hb[(n * 3 + (r - 1)) * 32 + c] = (u16)v;
    } else if (blk < 5064) {
        // ---------------- pi1 weight fusion: 12 columns of 768 ----------------
        const int cb0 = (blk - 5000) * 12;
        float* sW1  = smem;            // [64][32]  2048
        float* sW2  = smem + 2048;     // [32][96]  3072
        float* sW3c = smem + 5120;     // [96][12]  1152
        float* sU   = smem + 6272;     // [32][12]  384
        float* sbt  = smem + 6656;     // [96]
        for (int i = tid; i < 2048; i += 256) sW1[i] = W1[i];
        for (int i = tid; i < 3072; i += 256) sW2[i] = W2[i];
        for (int i = tid; i < 1152; i += 256) {
            int q = i / 12, u = i % 12;
            sW3c[i] = W3[q * 768 + cb0 + u];
        }
        __syncthreads();
        for (int t = tid; t < 480; t += 256) {
            if (t < 384) {
                int c2 = t / 12, u = t % 12;
                float a = 0.f;
                #pragma unroll 8
                for (int q = 0; q < 96; ++q) a += sW2[c2 * 96 + q] * sW3c[q * 12 + u];
                sU[t] = a;
            } else {
                int q = t - 384;
                float a = b2v[q];
                #pragma unroll 8
                for (int c2 = 0; c2 < 32; ++c2) a += b1v[c2] * sW2[c2 * 96 + q];
                sbt[q] = a;
            }
        }
        __syncthreads();
        for (int o = tid; o < 768; o += 256) {         // Wf1 panel
            int k = o / 12, u = o % 12;
            float a = 0.f;
            #pragma unroll 8
            for (int c2 = 0; c2 < 32; ++c2) a += sW1[k * 32 + c2] * sU[c2 * 12 + u];
            int cb = cb0 + u, b = cb & 7, c = cb >> 3;
            int nt = c >> 4, cL = c & 15;
            int ks = k >> 5, k5 = k & 31, Lhi = k5 >> 3, j = k5 & 7;
            wb[OWF1 + b * 6144 + nt * 1024 + ks * 512 + (Lhi * 16 + cL) * 8 + j] = (u16)f2b(a);
        }
        for (int o = tid; o < 48; o += 256) {          // BB1 (12 cols x 4 kg slots)
            int u = o >> 2, Lhi = o & 3;
            int x = cb0 + u;
            float a = 0.f;
            if (Lhi == 0) {
                #pragma unroll 8
                for (int q = 0; q < 96; ++q) a += sbt[q] * sW3c[q * 12 + u];
            }
            int j = x & 7, c = x >> 3, nt = c >> 4, cL = c & 15;
            wb[OBB1 + nt * 512 + (Lhi * 16 + cL) * 8 + j] = (u16)f2b(a);
        }
    } else if (blk < 5096) {
        // ---------------- pi3 weight fusion: 8 columns of 256 ----------------
        const int cb0 = (blk - 5064) * 8;
        float* sW13  = smem;           // [64][32] 2048
        float* sW23  = smem + 2048;    // [32][32] 1024
        float* sW33c = smem + 3072;    // [32][8]  256
        float* sU3   = smem + 3328;    // [32][8]  256
        float* sbt3  = smem + 3584;    // [32]
        for (int i = tid; i < 2048; i += 256) sW13[i] = W13[i];
        for (int i = tid; i < 1024; i += 256) sW23[i] = W23[i];
        for (int i = tid; i < 256; i += 256) {
            int q = i / 8, u = i % 8;
            sW33c[i] = W33[q * 256 + cb0 + u];
        }
        __syncthreads();
        for (int t = tid; t < 288; t += 256) {
            if (t < 256) {
                int c2 = t / 8, u = t % 8;
                float a = 0.f;
                #pragma unroll 8
                for (int q = 0; q < 32; ++q) a += sW23[c2 * 32 + q] * sW33c[q * 8 + u];
                sU3[t] = a;
            } else {
                int q = t - 256;
                float a = b23v[q];
                #pragma unroll 8
                for (int c2 = 0; c2 < 32; ++c2) a += b13v[c2] * sW23[c2 * 32 + q];
                sbt3[q] = a;
            }
        }
        __syncthreads();
        for (int o = tid; o < 512; o += 256) {         // Wf3 panel
            int k = o / 8, u = o % 8;
            float a = 0.f;
            #pragma unroll 8
            for (int c2 = 0; c2 < 32; ++c2) a += sW13[k * 32 + c2] * sU3[c2 * 8 + u];
            int cb = cb0 + u, b = cb & 7, c = cb >> 3;
            int nt = c >> 4, cL = c & 15;
            int ks = k >> 5, k5 = k & 31, Lhi = k5 >> 3, j = k5 & 7;
            wb[OWF3 + b * 2048 + nt * 1024 + ks * 512 + (Lhi * 16 + cL) * 8 + j] = (u16)f2b(a);
        }
        for (int o = tid; o < 32; o += 256) {          // BB3 (8 cols x 4 kg slots)
            int u = o >> 2, Lhi = o & 3;
            int x = cb0 + u;
            float a = 0.f;
            if (Lhi == 0) {
                #pragma unroll
                for (int q = 0; q < 32; ++q) a += sbt3[q] * sW33c[q * 8 + u];
            }
            int j = x & 7, c = x >> 3, nt = c >> 4, cL = c & 15;
            wb[OBB3 + nt * 512 + (Lhi * 16 + cL) * 8 + j] = (u16)f2b(a);
        }
    } else if (blk == 5096) {
        // ---------------- II1T / II3T copies ----------------
        for (int i = tid; i < 2048; i += 256) {
            if (i < 1024) {
                int nt = i >> 9, L = (i >> 3) & 63, j = i & 7;
                wb[OII1T + i] = (u16)f2b(ii1[((L >> 4) * 8 + j) * 32 + 16 * nt + (L & 15)]);
            } else {
                int i2 = i - 1024;
                int nt = i2 >> 9, L = (i2 >> 3) & 63, j = i2 & 7;
                wb[OII3T + i2] = (u16)f2b(ii3[((L >> 4) * 8 + j) * 32 + 16 * nt + (L & 15)]);
            }
        }
    } else {
        // ---------------- zero-init p1n & p3n (contiguous 5.12 MB) ----------
        float4 z = make_float4(0.f, 0.f, 0.f, 0.f);
        ((float4*)p1n)[(size_t)(blk - 5097) * 256 + tid] = z;
    }
}

// ------- fused edge kernel: 32 edges per 1-wave block (2 M-tiles) ---------
// Round-15/19/20/21 edge kernel EXACTLY ((64,3): empirical VGPR cap ~85 fits
// the 80-VGPR wave program; (64,4) caps at 64 -> spills). Measured ~107 us.
__global__ __launch_bounds__(64, 3) void edge_kernel(
    const u16* __restrict__ p1hb, const u16* __restrict__ p3hb,
    const float* __restrict__ r3, const float* __restrict__ basis,
    const int* __restrict__ idx_i, const int* __restrict__ idx_j,
    const u16* __restrict__ wb,
    const float* __restrict__ ii1b, const float* __restrict__ ii3b,
    float* __restrict__ p1n, float* __restrict__ p3n)
{
    // 3 KB LDS, single wave per block
    __shared__ int4 smem4[192];
    char* sw = (char*)smem4;
    int*   sIdxI = (int*)(sw + 0);       // [32]
    int*   sIdxJ = (int*)(sw + 128);     // [32]
    float* sBasT = (float*)(sw + 256);   // [8][32] transposed basis
    float* sR3   = (float*)(sw + 1280);  // [3][32]
    u16*   sT2   = (u16*)(sw + 1664);    // [16][40] transpose buffer

    const int l   = threadIdx.x & 63;
    const int r16 = l & 15;
    const int kg  = l >> 4;
    const int ebase = blockIdx.x * 32;

    // ---- staging (single wave: in-order LDS, no barriers) ----
    if (l < 32) sIdxI[l] = idx_i[ebase + l];
    else        sIdxJ[l - 32] = idx_j[ebase + l - 32];
    {
        int e = l & 31, hf = l >> 5;
        const float4* bp = (const float4*)(basis + (size_t)(ebase + e) * 8);
        float4 q = bp[hf];
        sBasT[(4 * hf + 0) * 32 + e] = q.x;
        sBasT[(4 * hf + 1) * 32 + e] = q.y;
        sBasT[(4 * hf + 2) * 32 + e] = q.z;
        sBasT[(4 * hf + 3) * 32 + e] = q.w;
        if (hf == 0) {
            sR3[e]      = r3[(size_t)(ebase + e) * 3 + 0];
            sR3[32 + e] = r3[(size_t)(ebase + e) * 3 + 1];
            sR3[64 + e] = r3[(size_t)(ebase + e) * 3 + 2];
        }
    }

    const float vii1[2] = { ii1b[r16], ii1b[16 + r16] };
    const float vii3[2] = { ii3b[r16], ii3b[16 + r16] };

    const f4v zf = {0.f, 0.f, 0.f, 0.f};

    // basis as K=8-padded A-fragment (for bias-init MFMAs)
    s8v bA[2];
    #pragma unroll
    for (int m = 0; m < 2; ++m) {
        s8v t;
        #pragma unroll
        for (int j = 0; j < 8; ++j)
            t[j] = (kg == 0) ? f2b(sBasT[j * 32 + m * 16 + r16]) : (short)0;
        bA[m] = t;
    }

    // ---- pi1: inter gathers (A-frags) ----
    s8v avI[2], avJ[2];
    #pragma unroll
    for (int m = 0; m < 2; ++m) {
        int rowA = m * 16 + r16;
        avI[m] = *(const s8v*)(p1hb + (size_t)sIdxI[rowA] * 32 + kg * 8);
        avJ[m] = *(const s8v*)(p1hb + (size_t)sIdxJ[rowA] * 32 + kg * 8);
    }

    // accT init = basis @ bf1  (bias term)
    f4v accT[2][6];
    {
        const u16* gBB = wb + OBB1;
        #pragma unroll
        for (int nt = 0; nt < 6; ++nt) {
            s8v bbv = *(const s8v*)(gBB + (nt * 64 + l) * 8);
            #pragma unroll
            for (int m = 0; m < 2; ++m)
                accT[m][nt] = __builtin_amdgcn_mfma_f32_16x16x32_bf16(bA[m], bbv, zf, 0, 0, 0);
        }
    }

    // ---- pi1 main: accT += basis_b * (inter @ Wf1_b) ----
    {
        const u16* gW = wb + OWF1;
        #pragma unroll 2
        for (int b = 0; b < 8; ++b) {
            float tb[2][4];
            #pragma unroll
            for (int m = 0; m < 2; ++m)
                #pragma unroll
                for (int rr = 0; rr < 4; ++rr)
                    tb[m][rr] = sBasT[b * 32 + m * 16 + 4 * kg + rr];
            #pragma unroll
            for (int nt = 0; nt < 6; ++nt) {
                const u16* bp = gW + ((size_t)(b * 6 + nt) * 2) * 512 + l * 8;
                s8v bv0 = *(const s8v*)(bp);
                s8v bv1 = *(const s8v*)(bp + 512);
                #pragma unroll
                for (int m = 0; m < 2; ++m) {
                    f4v D = __builtin_amdgcn_mfma_f32_16x16x32_bf16(avI[m], bv0, zf, 0, 0, 0);
                    D = __builtin_amdgcn_mfma_f32_16x16x32_bf16(avJ[m], bv1, D, 0, 0, 0);
                    #pragma unroll
                    for (int rr = 0; rr < 4; ++rr)
                        accT[m][nt][rr] += tb[m][rr] * D[rr];
                }
            }
        }
    }

    // ---- ii1: tanh(i1_1 @ ii1_W + b) -> atomic p1n[idx_j] ----
    {
        const u16* gII = wb + OII1T;
        #pragma unroll
        for (int m = 0; m < 2; ++m) {
            #pragma unroll
            for (int nt = 0; nt < 2; ++nt)
                #pragma unroll
                for (int rr = 0; rr < 4; ++rr)
                    sT2[(4 * kg + rr) * 40 + 16 * nt + r16] = (u16)f2b(accT[m][nt][rr]);
            s8v av = *(const s8v*)(sT2 + r16 * 40 + 8 * kg);
            #pragma unroll
            for (int nt = 0; nt < 2; ++nt) {
                s8v bv = *(const s8v*)(gII + (nt * 64 + l) * 8);
                f4v ia = __builtin_amdgcn_mfma_f32_16x16x32_bf16(av, bv, zf, 0, 0, 0);
                #pragma unroll
                for (int rr = 0; rr < 4; ++rr) {
                    int rowD = m * 16 + 4 * kg + rr;
                    atomicAdd(&p1n[(size_t)sIdxJ[rowD] * 32 + 16 * nt + r16],
                              tanhf_fast(ia[rr] + vii1[nt]));
                }
            }
        }
    }

    // ---- pi3 branch per Cartesian d ----
    const u16* gW3  = wb + OWF3;
    const u16* gBB3 = wb + OBB3;
    const u16* gII3 = wb + OII3T;
    for (int d = 0; d < 3; ++d) {
        s8v avI3[2], avJ3[2];
        #pragma unroll
        for (int m = 0; m < 2; ++m) {
            int rowA = m * 16 + r16;
            avI3[m] = *(const s8v*)(p3hb + ((size_t)sIdxI[rowA] * 3 + d) * 32 + kg * 8);
            avJ3[m] = *(const s8v*)(p3hb + ((size_t)sIdxJ[rowA] * 3 + d) * 32 + kg * 8);
        }
        f4v accP[2][2];
        #pragma unroll
        for (int nt = 0; nt < 2; ++nt) {
            s8v bbv = *(const s8v*)(gBB3 + (nt * 64 + l) * 8);
            #pragma unroll
            for (int m = 0; m < 2; ++m)
                accP[m][nt] = __builtin_amdgcn_mfma_f32_16x16x32_bf16(bA[m], bbv, zf, 0, 0, 0);
        }
        #pragma unroll 2
        for (int b = 0; b < 8; ++b) {
            float tb[2][4];
            #pragma unroll
            for (int m = 0; m < 2; ++m)
                #pragma unroll
                for (int rr = 0; rr < 4; ++rr)
                    tb[m][rr] = sBasT[b * 32 + m * 16 + 4 * kg + rr];
            #pragma unroll
            for (int nt = 0; nt < 2; ++nt) {
                const u16* bp = gW3 + ((size_t)(b * 2 + nt) * 2) * 512 + l * 8;
                s8v bv0 = *(const s8v*)(bp);
                s8v bv1 = *(const s8v*)(bp + 512);
                #pragma unroll
                for (int m = 0; m < 2; ++m) {
                    f4v D = __builtin_amdgcn_mfma_f32_16x16x32_bf16(avI3[m], bv0, zf, 0, 0, 0);
                    D = __builtin_amdgcn_mfma_f32_16x16x32_bf16(avJ3[m], bv1, D, 0, 0, 0);
                    #pragma unroll
                    for (int rr = 0; rr < 4; ++rr)
                        accP[m][nt][rr] += tb[m][rr] * D[rr];
                }
            }
        }
        // ii3 + combine + atomic p3n
        #pragma unroll
        for (int m = 0; m < 2; ++m) {
            #pragma unroll
            for (int nt = 0; nt < 2; ++nt)
                #pragma unroll
                for (int rr = 0; rr < 4; ++rr)
                    sT2[(4 * kg + rr) * 40 + 16 * nt + r16] = (u16)f2b(accP[m][nt][rr]);
            s8v av = *(const s8v*)(sT2 + r16 * 40 + 8 * kg);
            #pragma unroll
            for (int nt = 0; nt < 2; ++nt) {
                s8v bv = *(const s8v*)(gII3 + (nt * 64 + l) * 8);
                f4v ja = __builtin_amdgcn_mfma_f32_16x16x32_bf16(av, bv, zf, 0, 0, 0);
                #pragma unroll
                for (int rr = 0; rr < 4; ++rr) {
                    int rowD = m * 16 + 4 * kg + rr;
                    float i3a = tanhf_fast(ja[rr] + vii3[nt]);
                    float val = i3a * accT[m][2 + nt][rr] + sR3[d * 32 + rowD] * accT[m][4 + nt][rr];
                    atomicAdd(&p3n[((size_t)sIdxJ[rowD] * 3 + d) * 32 + 16 * nt + r16], val);
                }
            }
        }
    }
}

// ---------------- finalize: p1o = sum_d p3n^2 + p1n ; p3o = p3n * p1o -----
__global__ __launch_bounds__(256) void finalize_kernel(
    const float* __restrict__ p1n, const float* __restrict__ p3n,
    float* __restrict__ out)
{
    int t = blockIdx.x * 256 + threadIdx.x;
    int n = t >> 5, c = t & 31;
    float a0 = p3n[(n * 3 + 0) * 32 + c];
    float a1 = p3n[(n * 3 + 1) * 32 + c];
    float a2 = p3n[(n * 3 + 2) * 32 + c];
    float p1o = p1n[t] + a0 * a0 + a1 * a1 + a2 * a2;
    out[t] = p1o;
    float* o3 = out + NN * 32;
    o3[(n * 3 + 0) * 32 + c] = a0 * p1o;
    o3[(n * 3 + 1) * 32 + c] = a1 * p1o;
    o3[(n * 3 + 2) * 32 + c] = a2 * p1o;
}

extern "C" void kernel_launch(void* const* d_in, const int* in_sizes, int n_in,
                              void* d_out, int out_size, void* d_ws, size_t ws_size,
                              hipStream_t stream) {
    const float* p1     = (const float*)d_in[0];
    const float* p3     = (const float*)d_in[1];
    const float* r3     = (const float*)d_in[2];
    const float* basis  = (const float*)d_in[3];
    const int*   idx_i  = (const int*)d_in[4];
    const int*   idx_j  = (const int*)d_in[5];
    const float* pp1_W  = (const float*)d_in[6];
    const float* pp1_b  = (const float*)d_in[7];
    const float* pi1_W1 = (const float*)d_in[8];
    const float* pi1_b1 = (const float*)d_in[9];
    const float* pi1_W2 = (const float*)d_in[10];
    const float* pi1_b2 = (const float*)d_in[11];
    const float* pi1_W3 = (const float*)d_in[12];
    const float* ii1_W  = (const float*)d_in[13];
    const float* ii1_b  = (const float*)d_in[14];
    const float* pp3_W  = (const float*)d_in[15];
    const float* pp3_b  = (const float*)d_in[16];
    const float* pi3_W1 = (const float*)d_in[17];
    const float* pi3_b1 = (const float*)d_in[18];
    const float* pi3_W2 = (const float*)d_in[19];
    const float* pi3_b2 = (const float*)d_in[20];
    const float* pi3_W3 = (const float*)d_in[21];
    const float* ii3_W  = (const float*)d_in[22];
    const float* ii3_b  = (const float*)d_in[23];

    char* ws = (char*)d_ws;
    u16*   p1hb = (u16*)(ws + OFF_P1HB);
    u16*   p3hb = (u16*)(ws + OFF_P3HB);
    u16*   wb   = (u16*)(ws + OFF_WB);
    float* p1n  = (float*)(ws + OFF_P1N);
    float* p3n  = (float*)(ws + OFF_P3N);

    prep_kernel<<<dim3(6347), dim3(256), 0, stream>>>(
        p1, p3, pp1_W, pp1_b, pp3_W, pp3_b,
        pi1_W1, pi1_W2, pi1_W3, pi1_b1, pi1_b2, ii1_W,
        pi3_W1, pi3_W2, pi3_W3, pi3_b1, pi3_b2, ii3_W,
        p1hb, p3hb, wb, p1n);

    edge_kernel<<<dim3(NE / 32), dim3(64), 0, stream>>>(
        p1hb, p3hb, r3, basis, idx_i, idx_j, wb,
        ii1_b, ii3_b, p1n, p3n);

    finalize_kernel<<<dim3(1250), dim3(256), 0, stream>>>(p1n, p3n, (float*)d_out);
}

// Round 23
// 126.293 us; speedup vs baseline: 1.0806x; 1.0539x over previous
//
#include <hip/hip_runtime.h>
#include <math.h>

#define NN 10000
#define NE 160000

typedef __attribute__((ext_vector_type(8))) short s8v;
typedef __attribute__((ext_vector_type(4))) float f4v;
typedef unsigned short u16;

// ---- ws byte layout ----
#define OFF_P1HB 0u          // N*32 bf16      = 640000 B
#define OFF_P3HB 640000u     // N*3*32 bf16    = 1920000 B
#define OFF_WB   2560000u    // NWB u16        = 143360 B
#define OFF_P1N  2736640u    // N*32 f32       = 1280000 B
#define OFF_P3N  4016640u    // N*3*32 f32     = 3840000 B (contiguous after p1n)

// ---- wb (u16) offsets: fused weights, lane-consumption order [..][64][8] --
#define OWF1  0       // [b8][nt6][ks2][64][8] = 49152  (Wf1 = W1@W2@W3)
#define OBB1  49152   // [nt6][64][8]          = 3072   (bf1 folded, kg==0 else 0)
#define OII1T 52224   // [nt2][64][8]          = 1024
#define OWF3  53248   // [b8][nt2][ks2][64][8] = 16384  (Wf3 = W13@W23@W33)
#define OBB3  69632   // [nt2][64][8]          = 1024   (bf3 folded)
#define OII3T 70656   // [nt2][64][8]          = 1024
#define NWB   71680

__device__ __forceinline__ short f2b(float f) {
    unsigned u = __float_as_uint(f);
    u += 0x7fffu + ((u >> 16) & 1u);
    return (short)(u >> 16);
}
__device__ __forceinline__ float tanhf_fast(float x) {
    float xc = fminf(9.f, fmaxf(-9.f, x));
    float e = __expf(2.f * xc);
    return (e - 1.f) * __builtin_amdgcn_rcpf(e + 1.f);
}

// ============ single prep kernel, LONG BLOCKS FIRST ========================
// blk [0,64): pi1 fuse (12 cols each); [64,96): pi3 fuse (8 cols each);
// 96: II copies; [97,5097): node_prep; [5097,6347): zero p1n/p3n.
__global__ __launch_bounds__(256) void prep_kernel(
    const float* __restrict__ p1, const float* __restrict__ p3,
    const float* __restrict__ pp1_W, const float* __restrict__ pp1_b,
    const float* __restrict__ pp3_W, const float* __restrict__ pp3_b,
    const float* __restrict__ W1, const float* __restrict__ W2,
    const float* __restrict__ W3,
    const float* __restrict__ b1v, const float* __restrict__ b2v,
    const float* __restrict__ ii1,
    const float* __restrict__ W13, const float* __restrict__ W23,
    const float* __restrict__ W33,
    const float* __restrict__ b13v, const float* __restrict__ b23v,
    const float* __restrict__ ii3,
    u16* __restrict__ p1hb, u16* __restrict__ p3hb,
    u16* __restrict__ wb, float* __restrict__ p1n)
{
    __shared__ float smem[6912];       // 27648 B, role-dependent
    const int blk = blockIdx.x;
    const int tid = threadIdx.x;

    if (blk < 64) {
        // ---------------- pi1 weight fusion: 12 columns of 768 ----------------
        const int cb0 = blk * 12;
        float* sW1  = smem;            // [64][32]  2048
        float* sW2  = smem + 2048;     // [32][96]  3072
        float* sW3c = smem + 5120;     // [96][12]  1152
        float* sU   = smem + 6272;     // [32][12]  384
        float* sbt  = smem + 6656;     // [96]
        for (int i = tid; i < 2048; i += 256) sW1[i] = W1[i];
        for (int i = tid; i < 3072; i += 256) sW2[i] = W2[i];
        for (int i = tid; i < 1152; i += 256) {
            int q = i / 12, u = i % 12;
            sW3c[i] = W3[q * 768 + cb0 + u];
        }
        __syncthreads();
        for (int t = tid; t < 480; t += 256) {
            if (t < 384) {
                int c2 = t / 12, u = t % 12;
                float a = 0.f;
                #pragma unroll 8
                for (int q = 0; q < 96; ++q) a += sW2[c2 * 96 + q] * sW3c[q * 12 + u];
                sU[t] = a;
            } else {
                int q = t - 384;
                float a = b2v[q];
                #pragma unroll 8
                for (int c2 = 0; c2 < 32; ++c2) a += b1v[c2] * sW2[c2 * 96 + q];
                sbt[q] = a;
            }
        }
        __syncthreads();
        for (int o = tid; o < 768; o += 256) {         // Wf1 panel
            int k = o / 12, u = o % 12;
            float a = 0.f;
            #pragma unroll 8
            for (int c2 = 0; c2 < 32; ++c2) a += sW1[k * 32 + c2] * sU[c2 * 12 + u];
            int cb = cb0 + u, b = cb & 7, c = cb >> 3;
            int nt = c >> 4, cL = c & 15;
            int ks = k >> 5, k5 = k & 31, Lhi = k5 >> 3, j = k5 & 7;
            wb[OWF1 + b * 6144 + nt * 1024 + ks * 512 + (Lhi * 16 + cL) * 8 + j] = (u16)f2b(a);
        }
        for (int o = tid; o < 48; o += 256) {          // BB1 (12 cols x 4 kg slots)
            int u = o >> 2, Lhi = o & 3;
            int x = cb0 + u;
            float a = 0.f;
            if (Lhi == 0) {
                #pragma unroll 8
                for (int q = 0; q < 96; ++q) a += sbt[q] * sW3c[q * 12 + u];
            }
            int j = x & 7, c = x >> 3, nt = c >> 4, cL = c & 15;
            wb[OBB1 + nt * 512 + (Lhi * 16 + cL) * 8 + j] = (u16)f2b(a);
        }
    } else if (blk < 96) {
        // ---------------- pi3 weight fusion: 8 columns of 256 ----------------
        const int cb0 = (blk - 64) * 8;
        float* sW13  = smem;           // [64][32] 2048
        float* sW23  = smem + 2048;    // [32][32] 1024
        float* sW33c = smem + 3072;    // [32][8]  256
        float* sU3   = smem + 3328;    // [32][8]  256
        float* sbt3  = smem + 3584;    // [32]
        for (int i = tid; i < 2048; i += 256) sW13[i] = W13[i];
        for (int i = tid; i < 1024; i += 256) sW23[i] = W23[i];
        for (int i = tid; i < 256; i += 256) {
            int q = i / 8, u = i % 8;
            sW33c[i] = W33[q * 256 + cb0 + u];
        }
        __syncthreads();
        for (int t = tid; t < 288; t += 256) {
            if (t < 256) {
                int c2 = t / 8, u = t % 8;
                float a = 0.f;
                #pragma unroll 8
                for (int q = 0; q < 32; ++q) a += sW23[c2 * 32 + q] * sW33c[q * 8 + u];
                sU3[t] = a;
            } else {
                int q = t - 256;
                float a = b23v[q];
                #pragma unroll 8
                for (int c2 = 0; c2 < 32; ++c2) a += b13v[c2] * sW23[c2 * 32 + q];
                sbt3[q] = a;
            }
        }
        __syncthreads();
        for (int o = tid; o < 512; o += 256) {         // Wf3 panel
            int k = o / 8, u = o % 8;
            float a = 0.f;
            #pragma unroll 8
            for (int c2 = 0; c2 < 32; ++c2) a += sW13[k * 32 + c2] * sU3[c2 * 8 + u];
            int cb = cb0 + u, b = cb & 7, c = cb >> 3;
            int nt = c >> 4, cL = c & 15;
            int ks = k >> 5, k5 = k & 31, Lhi = k5 >> 3, j = k5 & 7;
            wb[OWF3 + b * 2048 + nt * 1024 + ks * 512 + (Lhi * 16 + cL) * 8 + j] = (u16)f2b(a);
        }
        for (int o = tid; o < 32; o += 256) {          // BB3 (8 cols x 4 kg slots)
            int u = o >> 2, Lhi = o & 3;
            int x = cb0 + u;
            float a = 0.f;
            if (Lhi == 0) {
                #pragma unroll
                for (int q = 0; q < 32; ++q) a += sbt3[q] * sW33c[q * 8 + u];
            }
            int j = x & 7, c = x >> 3, nt = c >> 4, cL = c & 15;
            wb[OBB3 + nt * 512 + (Lhi * 16 + cL) * 8 + j] = (u16)f2b(a);
        }
    } else if (blk == 96) {
        // ---------------- II1T / II3T copies ----------------
        for (int i = tid; i < 2048; i += 256) {
            if (i < 1024) {
                int nt = i >> 9, L = (i >> 3) & 63, j = i & 7;
                wb[OII1T + i] = (u16)f2b(ii1[((L >> 4) * 8 + j) * 32 + 16 * nt + (L & 15)]);
            } else {
                int i2 = i - 1024;
                int nt = i2 >> 9, L = (i2 >> 3) & 63, j = i2 & 7;
                wb[OII3T + i2] = (u16)f2b(ii3[((L >> 4) * 8 + j) * 32 + 16 * nt + (L & 15)]);
            }
        }
    } else if (blk < 5097) {
        // ---------------- node_prep ----------------
        float* Ws0 = smem;             // [1024]
        float* Ws1 = smem + 1024;      // [1024]
        float* bs0 = smem + 2048;      // [32]
        float* bs1 = smem + 2080;      // [32]
        for (int i = tid; i < 1024; i += 256) { Ws0[i] = pp1_W[i]; Ws1[i] = pp3_W[i]; }
        if (tid < 32) { bs0[tid] = pp1_b[tid]; bs1[tid] = pp3_b[tid]; }
        __syncthreads();
        int idx = (blk - 97) * 256 + tid;
        int n = idx >> 7;
        int r = (idx >> 5) & 3;
        int c = idx & 31;
        const float* Ws = (r == 0) ? Ws0 : Ws1;
        const float* bs = (r == 0) ? bs0 : bs1;
        const float* in = (r == 0) ? (p1 + n * 32) : (p3 + (n * 3 + (r - 1)) * 32);
        float acc = bs[c];
        #pragma unroll
        for (int k = 0; k < 32; ++k) acc += in[k] * Ws[k * 32 + c];
        short v = f2b(tanhf(acc));
        if (r == 0) p1hb[n * 32 + c] = (u16)v;
        else        p3hb[(n * 3 + (r - 1)) * 32 + c] = (u16)v;
    } else {
        // ---------------- zero-init p1n & p3n (contiguous 5.12 MB) ----------
        float4 z = make_float4(0.f, 0.f, 0.f, 0.f);
        ((float4*)p1n)[(size_t)(blk - 5097) * 256 + tid] = z;
    }
}

// ------- fused edge kernel: 32 edges per 1-wave block (2 M-tiles) ---------
// Round-15/19/20/21/22 edge kernel EXACTLY ((64,3): empirical VGPR cap ~85
// fits the 80-VGPR wave program; (64,4) caps at 64 -> spills). ~107 us.
__global__ __launch_bounds__(64, 3) void edge_kernel(
    const u16* __restrict__ p1hb, const u16* __restrict__ p3hb,
    const float* __restrict__ r3, const float* __restrict__ basis,
    const int* __restrict__ idx_i, const int* __restrict__ idx_j,
    const u16* __restrict__ wb,
    const float* __restrict__ ii1b, const float* __restrict__ ii3b,
    float* __restrict__ p1n, float* __restrict__ p3n)
{
    // 3 KB LDS, single wave per block
    __shared__ int4 smem4[192];
    char* sw = (char*)smem4;
    int*   sIdxI = (int*)(sw + 0);       // [32]
    int*   sIdxJ = (int*)(sw + 128);     // [32]
    float* sBasT = (float*)(sw + 256);   // [8][32] transposed basis
    float* sR3   = (float*)(sw + 1280);  // [3][32]
    u16*   sT2   = (u16*)(sw + 1664);    // [16][40] transpose buffer

    const int l   = threadIdx.x & 63;
    const int r16 = l & 15;
    const int kg  = l >> 4;
    const int ebase = blockIdx.x * 32;

    // ---- staging (single wave: in-order LDS, no barriers) ----
    if (l < 32) sIdxI[l] = idx_i[ebase + l];
    else        sIdxJ[l - 32] = idx_j[ebase + l - 32];
    {
        int e = l & 31, hf = l >> 5;
        const float4* bp = (const float4*)(basis + (size_t)(ebase + e) * 8);
        float4 q = bp[hf];
        sBasT[(4 * hf + 0) * 32 + e] = q.x;
        sBasT[(4 * hf + 1) * 32 + e] = q.y;
        sBasT[(4 * hf + 2) * 32 + e] = q.z;
        sBasT[(4 * hf + 3) * 32 + e] = q.w;
        if (hf == 0) {
            sR3[e]      = r3[(size_t)(ebase + e) * 3 + 0];
            sR3[32 + e] = r3[(size_t)(ebase + e) * 3 + 1];
            sR3[64 + e] = r3[(size_t)(ebase + e) * 3 + 2];
        }
    }

    const float vii1[2] = { ii1b[r16], ii1b[16 + r16] };
    const float vii3[2] = { ii3b[r16], ii3b[16 + r16] };

    const f4v zf = {0.f, 0.f, 0.f, 0.f};

    // basis as K=8-padded A-fragment (for bias-init MFMAs)
    s8v bA[2];
    #pragma unroll
    for (int m = 0; m < 2; ++m) {
        s8v t;
        #pragma unroll
        for (int j = 0; j < 8; ++j)
            t[j] = (kg == 0) ? f2b(sBasT[j * 32 + m * 16 + r16]) : (short)0;
        bA[m] = t;
    }

    // ---- pi1: inter gathers (A-frags) ----
    s8v avI[2], avJ[2];
    #pragma unroll
    for (int m = 0; m < 2; ++m) {
        int rowA = m * 16 + r16;
        avI[m] = *(const s8v*)(p1hb + (size_t)sIdxI[rowA] * 32 + kg * 8);
        avJ[m] = *(const s8v*)(p1hb + (size_t)sIdxJ[rowA] * 32 + kg * 8);
    }

    // accT init = basis @ bf1  (bias term)
    f4v accT[2][6];
    {
        const u16* gBB = wb + OBB1;
        #pragma unroll
        for (int nt = 0; nt < 6; ++nt) {
            s8v bbv = *(const s8v*)(gBB + (nt * 64 + l) * 8);
            #pragma unroll
            for (int m = 0; m < 2; ++m)
                accT[m][nt] = __builtin_amdgcn_mfma_f32_16x16x32_bf16(bA[m], bbv, zf, 0, 0, 0);
        }
    }

    // ---- pi1 main: accT += basis_b * (inter @ Wf1_b) ----
    {
        const u16* gW = wb + OWF1;
        #pragma unroll 2
        for (int b = 0; b < 8; ++b) {
            float tb[2][4];
            #pragma unroll
            for (int m = 0; m < 2; ++m)
                #pragma unroll
                for (int rr = 0; rr < 4; ++rr)
                    tb[m][rr] = sBasT[b * 32 + m * 16 + 4 * kg + rr];
            #pragma unroll
            for (int nt = 0; nt < 6; ++nt) {
                const u16* bp = gW + ((size_t)(b * 6 + nt) * 2) * 512 + l * 8;
                s8v bv0 = *(const s8v*)(bp);
                s8v bv1 = *(const s8v*)(bp + 512);
                #pragma unroll
                for (int m = 0; m < 2; ++m) {
                    f4v D = __builtin_amdgcn_mfma_f32_16x16x32_bf16(avI[m], bv0, zf, 0, 0, 0);
                    D = __builtin_amdgcn_mfma_f32_16x16x32_bf16(avJ[m], bv1, D, 0, 0, 0);
                    #pragma unroll
                    for (int rr = 0; rr < 4; ++rr)
                        accT[m][nt][rr] += tb[m][rr] * D[rr];
                }
            }
        }
    }

    // ---- ii1: tanh(i1_1 @ ii1_W + b) -> atomic p1n[idx_j] ----
    {
        const u16* gII = wb + OII1T;
        #pragma unroll
        for (int m = 0; m < 2; ++m) {
            #pragma unroll
            for (int nt = 0; nt < 2; ++nt)
                #pragma unroll
                for (int rr = 0; rr < 4; ++rr)
                    sT2[(4 * kg + rr) * 40 + 16 * nt + r16] = (u16)f2b(accT[m][nt][rr]);
            s8v av = *(const s8v*)(sT2 + r16 * 40 + 8 * kg);
            #pragma unroll
            for (int nt = 0; nt < 2; ++nt) {
                s8v bv = *(const s8v*)(gII + (nt * 64 + l) * 8);
                f4v ia = __builtin_amdgcn_mfma_f32_16x16x32_bf16(av, bv, zf, 0, 0, 0);
                #pragma unroll
                for (int rr = 0; rr < 4; ++rr) {
                    int rowD = m * 16 + 4 * kg + rr;
                    atomicAdd(&p1n[(size_t)sIdxJ[rowD] * 32 + 16 * nt + r16],
                              tanhf_fast(ia[rr] + vii1[nt]));
                }
            }
        }
    }

    // ---- pi3 branch per Cartesian d ----
    const u16* gW3  = wb + OWF3;
    const u16* gBB3 = wb + OBB3;
    const u16* gII3 = wb + OII3T;
    for (int d = 0; d < 3; ++d) {
        s8v avI3[2], avJ3[2];
        #pragma unroll
        for (int m = 0; m < 2; ++m) {
            int rowA = m * 16 + r16;
            avI3[m] = *(const s8v*)(p3hb + ((size_t)sIdxI[rowA] * 3 + d) * 32 + kg * 8);
            avJ3[m] = *(const s8v*)(p3hb + ((size_t)sIdxJ[rowA] * 3 + d) * 32 + kg * 8);
        }
        f4v accP[2][2];
        #pragma unroll
        for (int nt = 0; nt < 2; ++nt) {
            s8v bbv = *(const s8v*)(gBB3 + (nt * 64 + l) * 8);
            #pragma unroll
            for (int m = 0; m < 2; ++m)
                accP[m][nt] = __builtin_amdgcn_mfma_f32_16x16x32_bf16(bA[m], bbv, zf, 0, 0, 0);
        }
        #pragma unroll 2
        for (int b = 0; b < 8; ++b) {
            float tb[2][4];
            #pragma unroll
            for (int m = 0; m < 2; ++m)
                #pragma unroll
                for (int rr = 0; rr < 4; ++rr)
                    tb[m][rr] = sBasT[b * 32 + m * 16 + 4 * kg + rr];
            #pragma unroll
            for (int nt = 0; nt < 2; ++nt) {
                const u16* bp = gW3 + ((size_t)(b * 2 + nt) * 2) * 512 + l * 8;
                s8v bv0 = *(const s8v*)(bp);
                s8v bv1 = *(const s8v*)(bp + 512);
                #pragma unroll
                for (int m = 0; m < 2; ++m) {
                    f4v D = __builtin_amdgcn_mfma_f32_16x16x32_bf16(avI3[m], bv0, zf, 0, 0, 0);
                    D = __builtin_amdgcn_mfma_f32_16x16x32_bf16(avJ3[m], bv1, D, 0, 0, 0);
                    #pragma unroll
                    for (int rr = 0; rr < 4; ++rr)
                        accP[m][nt][rr] += tb[m][rr] * D[rr];
                }
            }
        }
        // ii3 + combine + atomic p3n
        #pragma unroll
        for (int m = 0; m < 2; ++m) {
            #pragma unroll
            for (int nt = 0; nt < 2; ++nt)
                #pragma unroll
                for (int rr = 0; rr < 4; ++rr)
                    sT2[(4 * kg + rr) * 40 + 16 * nt + r16] = (u16)f2b(accP[m][nt][rr]);
            s8v av = *(const s8v*)(sT2 + r16 * 40 + 8 * kg);
            #pragma unroll
            for (int nt = 0; nt < 2; ++nt) {
                s8v bv = *(const s8v*)(gII3 + (nt * 64 + l) * 8);
                f4v ja = __builtin_amdgcn_mfma_f32_16x16x32_bf16(av, bv, zf, 0, 0, 0);
                #pragma unroll
                for (int rr = 0; rr < 4; ++rr) {
                    int rowD = m * 16 + 4 * kg + rr;
                    float i3a = tanhf_fast(ja[rr] + vii3[nt]);
                    float val = i3a * accT[m][2 + nt][rr] + sR3[d * 32 + rowD] * accT[m][4 + nt][rr];
                    atomicAdd(&p3n[((size_t)sIdxJ[rowD] * 3 + d) * 32 + 16 * nt + r16], val);
                }
            }
        }
    }
}

// ---------------- finalize: p1o = sum_d p3n^2 + p1n ; p3o = p3n * p1o -----
__global__ __launch_bounds__(256) void finalize_kernel(
    const float* __restrict__ p1n, const float* __restrict__ p3n,
    float* __restrict__ out)
{
    int t = blockIdx.x * 256 + threadIdx.x;
    int n = t >> 5, c = t & 31;
    float a0 = p3n[(n * 3 + 0) * 32 + c];
    float a1 = p3n[(n * 3 + 1) * 32 + c];
    float a2 = p3n[(n * 3 + 2) * 32 + c];
    float p1o = p1n[t] + a0 * a0 + a1 * a1 + a2 * a2;
    out[t] = p1o;
    float* o3 = out + NN * 32;
    o3[(n * 3 + 0) * 32 + c] = a0 * p1o;
    o3[(n * 3 + 1) * 32 + c] = a1 * p1o;
    o3[(n * 3 + 2) * 32 + c] = a2 * p1o;
}

extern "C" void kernel_launch(void* const* d_in, const int* in_sizes, int n_in,
                              void* d_out, int out_size, void* d_ws, size_t ws_size,
                              hipStream_t stream) {
    const float* p1     = (const float*)d_in[0];
    const float* p3     = (const float*)d_in[1];
    const float* r3     = (const float*)d_in[2];
    const float* basis  = (const float*)d_in[3];
    const int*   idx_i  = (const int*)d_in[4];
    const int*   idx_j  = (const int*)d_in[5];
    const float* pp1_W  = (const float*)d_in[6];
    const float* pp1_b  = (const float*)d_in[7];
    const float* pi1_W1 = (const float*)d_in[8];
    const float* pi1_b1 = (const float*)d_in[9];
    const float* pi1_W2 = (const float*)d_in[10];
    const float* pi1_b2 = (const float*)d_in[11];
    const float* pi1_W3 = (const float*)d_in[12];
    const float* ii1_W  = (const float*)d_in[13];
    const float* ii1_b  = (const float*)d_in[14];
    const float* pp3_W  = (const float*)d_in[15];
    const float* pp3_b  = (const float*)d_in[16];
    const float* pi3_W1 = (const float*)d_in[17];
    const float* pi3_b1 = (const float*)d_in[18];
    const float* pi3_W2 = (const float*)d_in[19];
    const float* pi3_b2 = (const float*)d_in[20];
    const float* pi3_W3 = (const float*)d_in[21];
    const float* ii3_W  = (const float*)d_in[22];
    const float* ii3_b  = (const float*)d_in[23];

    char* ws = (char*)d_ws;
    u16*   p1hb = (u16*)(ws + OFF_P1HB);
    u16*   p3hb = (u16*)(ws + OFF_P3HB);
    u16*   wb   = (u16*)(ws + OFF_WB);
    float* p1n  = (float*)(ws + OFF_P1N);
    float* p3n  = (float*)(ws + OFF_P3N);

    prep_kernel<<<dim3(6347), dim3(256), 0, stream>>>(
        p1, p3, pp1_W, pp1_b, pp3_W, pp3_b,
        pi1_W1, pi1_W2, pi1_W3, pi1_b1, pi1_b2, ii1_W,
        pi3_W1, pi3_W2, pi3_W3, pi3_b1, pi3_b2, ii3_W,
        p1hb, p3hb, wb, p1n);

    edge_kernel<<<dim3(NE / 32), dim3(64), 0, stream>>>(
        p1hb, p3hb, r3, basis, idx_i, idx_j, wb,
        ii1_b, ii3_b, p1n, p3n);

    finalize_kernel<<<dim3(1250), dim3(256), 0, stream>>>(p1n, p3n, (float*)d_out);
}

// Round 24
// 125.085 us; speedup vs baseline: 1.0911x; 1.0097x over previous
//
#include <hip/hip_runtime.h>
#include <math.h>

#define NN 10000
#define NE 160000

typedef __attribute__((ext_vector_type(8))) short s8v;
typedef __attribute__((ext_vector_type(4))) float f4v;
typedef unsigned short u16;

// ---- ws byte layout ----
#define OFF_P1HB 0u          // N*32 bf16      = 640000 B
#define OFF_P3HB 640000u     // N*3*32 bf16    = 1920000 B
#define OFF_WB   2560000u    // NWB u16        = 143360 B
#define OFF_P1N  2736640u    // N*32 f32       = 1280000 B
#define OFF_P3N  4016640u    // N*3*32 f32     = 3840000 B (contiguous after p1n)

// ---- wb (u16) offsets: fused weights, lane-consumption order [..][64][8] --
#define OWF1  0       // [b8][nt6][ks2][64][8] = 49152  (Wf1 = W1@W2@W3)
#define OBB1  49152   // [nt6][64][8]          = 3072   (bf1 folded, kg==0 else 0)
#define OII1T 52224   // [nt2][64][8]          = 1024
#define OWF3  53248   // [b8][nt2][ks2][64][8] = 16384  (Wf3 = W13@W23@W33)
#define OBB3  69632   // [nt2][64][8]          = 1024   (bf3 folded)
#define OII3T 70656   // [nt2][64][8]          = 1024
#define NWB   71680

__device__ __forceinline__ short f2b(float f) {
    unsigned u = __float_as_uint(f);
    u += 0x7fffu + ((u >> 16) & 1u);
    return (short)(u >> 16);
}
__device__ __forceinline__ float tanhf_fast(float x) {
    float xc = fminf(9.f, fmaxf(-9.f, x));
    float e = __expf(2.f * xc);
    return (e - 1.f) * __builtin_amdgcn_rcpf(e + 1.f);
}

// ============ single prep kernel, LONG BLOCKS FIRST ========================
// blk [0,64): pi1 fuse (12 cols each); [64,96): pi3 fuse (8 cols each);
// 96: II copies; [97,5097): node_prep; [5097,6347): zero p1n/p3n.
__global__ __launch_bounds__(256) void prep_kernel(
    const float* __restrict__ p1, const float* __restrict__ p3,
    const float* __restrict__ pp1_W, const float* __restrict__ pp1_b,
    const float* __restrict__ pp3_W, const float* __restrict__ pp3_b,
    const float* __restrict__ W1, const float* __restrict__ W2,
    const float* __restrict__ W3,
    const float* __restrict__ b1v, const float* __restrict__ b2v,
    const float* __restrict__ ii1,
    const float* __restrict__ W13, const float* __restrict__ W23,
    const float* __restrict__ W33,
    const float* __restrict__ b13v, const float* __restrict__ b23v,
    const float* __restrict__ ii3,
    u16* __restrict__ p1hb, u16* __restrict__ p3hb,
    u16* __restrict__ wb, float* __restrict__ p1n)
{
    __shared__ float smem[6912];       // 27648 B, role-dependent
    const int blk = blockIdx.x;
    const int tid = threadIdx.x;

    if (blk < 64) {
        // ---------------- pi1 weight fusion: 12 columns of 768 ----------------
        const int cb0 = blk * 12;
        float* sW1  = smem;            // [64][32]  2048
        float* sW2  = smem + 2048;     // [32][96]  3072
        float* sW3c = smem + 5120;     // [96][12]  1152
        float* sU   = smem + 6272;     // [32][12]  384
        float* sbt  = smem + 6656;     // [96]
        for (int i = tid; i < 2048; i += 256) sW1[i] = W1[i];
        for (int i = tid; i < 3072; i += 256) sW2[i] = W2[i];
        for (int i = tid; i < 1152; i += 256) {
            int q = i / 12, u = i % 12;
            sW3c[i] = W3[q * 768 + cb0 + u];
        }
        __syncthreads();
        for (int t = tid; t < 480; t += 256) {
            if (t < 384) {
                int c2 = t / 12, u = t % 12;
                float a = 0.f;
                #pragma unroll 8
                for (int q = 0; q < 96; ++q) a += sW2[c2 * 96 + q] * sW3c[q * 12 + u];
                sU[t] = a;
            } else {
                int q = t - 384;
                float a = b2v[q];
                #pragma unroll 8
                for (int c2 = 0; c2 < 32; ++c2) a += b1v[c2] * sW2[c2 * 96 + q];
                sbt[q] = a;
            }
        }
        __syncthreads();
        for (int o = tid; o < 768; o += 256) {         // Wf1 panel
            int k = o / 12, u = o % 12;
            float a = 0.f;
            #pragma unroll 8
            for (int c2 = 0; c2 < 32; ++c2) a += sW1[k * 32 + c2] * sU[c2 * 12 + u];
            int cb = cb0 + u, b = cb & 7, c = cb >> 3;
            int nt = c >> 4, cL = c & 15;
            int ks = k >> 5, k5 = k & 31, Lhi = k5 >> 3, j = k5 & 7;
            wb[OWF1 + b * 6144 + nt * 1024 + ks * 512 + (Lhi * 16 + cL) * 8 + j] = (u16)f2b(a);
        }
        for (int o = tid; o < 48; o += 256) {          // BB1 (12 cols x 4 kg slots)
            int u = o >> 2, Lhi = o & 3;
            int x = cb0 + u;
            float a = 0.f;
            if (Lhi == 0) {
                #pragma unroll 8
                for (int q = 0; q < 96; ++q) a += sbt[q] * sW3c[q * 12 + u];
            }
            int j = x & 7, c = x >> 3, nt = c >> 4, cL = c & 15;
            wb[OBB1 + nt * 512 + (Lhi * 16 + cL) * 8 + j] = (u16)f2b(a);
        }
    } else if (blk < 96) {
        // ---------------- pi3 weight fusion: 8 columns of 256 ----------------
        const int cb0 = (blk - 64) * 8;
        float* sW13  = smem;           // [64][32] 2048
        float* sW23  = smem + 2048;    // [32][32] 1024
        float* sW33c = smem + 3072;    // [32][8]  256
        float* sU3   = smem + 3328;    // [32][8]  256
        float* sbt3  = smem + 3584;    // [32]
        for (int i = tid; i < 2048; i += 256) sW13[i] = W13[i];
        for (int i = tid; i < 1024; i += 256) sW23[i] = W23[i];
        for (int i = tid; i < 256; i += 256) {
            int q = i / 8, u = i % 8;
            sW33c[i] = W33[q * 256 + cb0 + u];
        }
        __syncthreads();
        for (int t = tid; t < 288; t += 256) {
            if (t < 256) {
                int c2 = t / 8, u = t % 8;
                float a = 0.f;
                #pragma unroll 8
                for (int q = 0; q < 32; ++q) a += sW23[c2 * 32 + q] * sW33c[q * 8 + u];
                sU3[t] = a;
            } else {
                int q = t - 256;
                float a = b23v[q];
                #pragma unroll 8
                for (int c2 = 0; c2 < 32; ++c2) a += b13v[c2] * sW23[c2 * 32 + q];
                sbt3[q] = a;
            }
        }
        __syncthreads();
        for (int o = tid; o < 512; o += 256) {         // Wf3 panel
            int k = o / 8, u = o % 8;
            float a = 0.f;
            #pragma unroll 8
            for (int c2 = 0; c2 < 32; ++c2) a += sW13[k * 32 + c2] * sU3[c2 * 8 + u];
            int cb = cb0 + u, b = cb & 7, c = cb >> 3;
            int nt = c >> 4, cL = c & 15;
            int ks = k >> 5, k5 = k & 31, Lhi = k5 >> 3, j = k5 & 7;
            wb[OWF3 + b * 2048 + nt * 1024 + ks * 512 + (Lhi * 16 + cL) * 8 + j] = (u16)f2b(a);
        }
        for (int o = tid; o < 32; o += 256) {          // BB3 (8 cols x 4 kg slots)
            int u = o >> 2, Lhi = o & 3;
            int x = cb0 + u;
            float a = 0.f;
            if (Lhi == 0) {
                #pragma unroll
                for (int q = 0; q < 32; ++q) a += sbt3[q] * sW33c[q * 8 + u];
            }
            int j = x & 7, c = x >> 3, nt = c >> 4, cL = c & 15;
            wb[OBB3 + nt * 512 + (Lhi * 16 + cL) * 8 + j] = (u16)f2b(a);
        }
    } else if (blk == 96) {
        // ---------------- II1T / II3T copies ----------------
        for (int i = tid; i < 2048; i += 256) {
            if (i < 1024) {
                int nt = i >> 9, L = (i >> 3) & 63, j = i & 7;
                wb[OII1T + i] = (u16)f2b(ii1[((L >> 4) * 8 + j) * 32 + 16 * nt + (L & 15)]);
            } else {
                int i2 = i - 1024;
                int nt = i2 >> 9, L = (i2 >> 3) & 63, j = i2 & 7;
                wb[OII3T + i2] = (u16)f2b(ii3[((L >> 4) * 8 + j) * 32 + 16 * nt + (L & 15)]);
            }
        }
    } else if (blk < 5097) {
        // ---------------- node_prep ----------------
        float* Ws0 = smem;             // [1024]
        float* Ws1 = smem + 1024;      // [1024]
        float* bs0 = smem + 2048;      // [32]
        float* bs1 = smem + 2080;      // [32]
        for (int i = tid; i < 1024; i += 256) { Ws0[i] = pp1_W[i]; Ws1[i] = pp3_W[i]; }
        if (tid < 32) { bs0[tid] = pp1_b[tid]; bs1[tid] = pp3_b[tid]; }
        __syncthreads();
        int idx = (blk - 97) * 256 + tid;
        int n = idx >> 7;
        int r = (idx >> 5) & 3;
        int c = idx & 31;
        const float* Ws = (r == 0) ? Ws0 : Ws1;
        const float* bs = (r == 0) ? bs0 : bs1;
        const float* in = (r == 0) ? (p1 + n * 32) : (p3 + (n * 3 + (r - 1)) * 32);
        float acc = bs[c];
        #pragma unroll
        for (int k = 0; k < 32; ++k) acc += in[k] * Ws[k * 32 + c];
        short v = f2b(tanhf(acc));
        if (r == 0) p1hb[n * 32 + c] = (u16)v;
        else        p3hb[(n * 3 + (r - 1)) * 32 + c] = (u16)v;
    } else {
        // ---------------- zero-init p1n & p3n (contiguous 5.12 MB) ----------
        float4 z = make_float4(0.f, 0.f, 0.f, 0.f);
        ((float4*)p1n)[(size_t)(blk - 5097) * 256 + tid] = z;
    }
}

// ------- fused edge kernel: 16 edges per 1-wave block (M=1) ---------------
// Fused weights cut per-wave weight reads to ~134 KB, so 10000 waves imply
// only 1.34 GB L2 traffic (round-11's M=1 failure was 3.2 GB). Regs ~60
// (< (64,3) cap ~85). 2x wave supply vs round 23.
__global__ __launch_bounds__(64, 3) void edge_kernel(
    const u16* __restrict__ p1hb, const u16* __restrict__ p3hb,
    const float* __restrict__ r3, const float* __restrict__ basis,
    const int* __restrict__ idx_i, const int* __restrict__ idx_j,
    const u16* __restrict__ wb,
    const float* __restrict__ ii1b, const float* __restrict__ ii3b,
    float* __restrict__ p1n, float* __restrict__ p3n)
{
    // 2.1 KB LDS, single wave per block
    __shared__ int4 smem4[136];
    char* sw = (char*)smem4;
    int*   sIdxI = (int*)(sw + 0);       // [16]
    int*   sIdxJ = (int*)(sw + 64);      // [16]
    float* sBasT = (float*)(sw + 128);   // [8][16] transposed basis
    float* sR3   = (float*)(sw + 640);   // [3][16]
    u16*   sT2   = (u16*)(sw + 832);     // [16][40] transpose buffer

    const int l   = threadIdx.x & 63;
    const int r16 = l & 15;
    const int kg  = l >> 4;
    const int ebase = blockIdx.x * 16;

    // ---- staging (single wave: in-order LDS, no barriers) ----
    if (l < 16)      sIdxI[l] = idx_i[ebase + l];
    else if (l < 32) sIdxJ[l - 16] = idx_j[ebase + l - 16];
    else if (l < 48) {
        int e = l - 32;
        sR3[e]      = r3[(size_t)(ebase + e) * 3 + 0];
        sR3[16 + e] = r3[(size_t)(ebase + e) * 3 + 1];
        sR3[32 + e] = r3[(size_t)(ebase + e) * 3 + 2];
    }
    if (l < 32) {
        int e = l >> 1, hf = l & 1;
        float4 q = ((const float4*)(basis + (size_t)(ebase + e) * 8))[hf];
        sBasT[(4 * hf + 0) * 16 + e] = q.x;
        sBasT[(4 * hf + 1) * 16 + e] = q.y;
        sBasT[(4 * hf + 2) * 16 + e] = q.z;
        sBasT[(4 * hf + 3) * 16 + e] = q.w;
    }

    const float vii1[2] = { ii1b[r16], ii1b[16 + r16] };
    const float vii3[2] = { ii3b[r16], ii3b[16 + r16] };

    const f4v zf = {0.f, 0.f, 0.f, 0.f};

    // basis as K=8-padded A-fragment (for bias-init MFMAs)
    s8v bA;
    {
        s8v t;
        #pragma unroll
        for (int j = 0; j < 8; ++j)
            t[j] = (kg == 0) ? f2b(sBasT[j * 16 + r16]) : (short)0;
        bA = t;
    }

    // ---- pi1: inter gathers (A-frags) ----
    s8v avI = *(const s8v*)(p1hb + (size_t)sIdxI[r16] * 32 + kg * 8);
    s8v avJ = *(const s8v*)(p1hb + (size_t)sIdxJ[r16] * 32 + kg * 8);

    // accT init = basis @ bf1  (bias term)
    f4v accT[6];
    {
        const u16* gBB = wb + OBB1;
        #pragma unroll
        for (int nt = 0; nt < 6; ++nt) {
            s8v bbv = *(const s8v*)(gBB + (nt * 64 + l) * 8);
            accT[nt] = __builtin_amdgcn_mfma_f32_16x16x32_bf16(bA, bbv, zf, 0, 0, 0);
        }
    }

    // ---- pi1 main: accT += basis_b * (inter @ Wf1_b) ----
    {
        const u16* gW = wb + OWF1;
        #pragma unroll 2
        for (int b = 0; b < 8; ++b) {
            float tb[4];
            #pragma unroll
            for (int rr = 0; rr < 4; ++rr)
                tb[rr] = sBasT[b * 16 + 4 * kg + rr];
            #pragma unroll
            for (int nt = 0; nt < 6; ++nt) {
                const u16* bp = gW + ((size_t)(b * 6 + nt) * 2) * 512 + l * 8;
                s8v bv0 = *(const s8v*)(bp);
                s8v bv1 = *(const s8v*)(bp + 512);
                f4v D = __builtin_amdgcn_mfma_f32_16x16x32_bf16(avI, bv0, zf, 0, 0, 0);
                D = __builtin_amdgcn_mfma_f32_16x16x32_bf16(avJ, bv1, D, 0, 0, 0);
                #pragma unroll
                for (int rr = 0; rr < 4; ++rr)
                    accT[nt][rr] += tb[rr] * D[rr];
            }
        }
    }

    // ---- ii1: tanh(i1_1 @ ii1_W + b) -> atomic p1n[idx_j] ----
    {
        const u16* gII = wb + OII1T;
        #pragma unroll
        for (int nt = 0; nt < 2; ++nt)
            #pragma unroll
            for (int rr = 0; rr < 4; ++rr)
                sT2[(4 * kg + rr) * 40 + 16 * nt + r16] = (u16)f2b(accT[nt][rr]);
        s8v av = *(const s8v*)(sT2 + r16 * 40 + 8 * kg);
        #pragma unroll
        for (int nt = 0; nt < 2; ++nt) {
            s8v bv = *(const s8v*)(gII + (nt * 64 + l) * 8);
            f4v ia = __builtin_amdgcn_mfma_f32_16x16x32_bf16(av, bv, zf, 0, 0, 0);
            #pragma unroll
            for (int rr = 0; rr < 4; ++rr) {
                int rowD = 4 * kg + rr;
                atomicAdd(&p1n[(size_t)sIdxJ[rowD] * 32 + 16 * nt + r16],
                          tanhf_fast(ia[rr] + vii1[nt]));
            }
        }
    }

    // ---- pi3 branch per Cartesian d ----
    const u16* gW3  = wb + OWF3;
    const u16* gBB3 = wb + OBB3;
    const u16* gII3 = wb + OII3T;
    for (int d = 0; d < 3; ++d) {
        s8v avI3 = *(const s8v*)(p3hb + ((size_t)sIdxI[r16] * 3 + d) * 32 + kg * 8);
        s8v avJ3 = *(const s8v*)(p3hb + ((size_t)sIdxJ[r16] * 3 + d) * 32 + kg * 8);
        f4v accP[2];
        #pragma unroll
        for (int nt = 0; nt < 2; ++nt) {
            s8v bbv = *(const s8v*)(gBB3 + (nt * 64 + l) * 8);
            accP[nt] = __builtin_amdgcn_mfma_f32_16x16x32_bf16(bA, bbv, zf, 0, 0, 0);
        }
        #pragma unroll 2
        for (int b = 0; b < 8; ++b) {
            float tb[4];
            #pragma unroll
            for (int rr = 0; rr < 4; ++rr)
                tb[rr] = sBasT[b * 16 + 4 * kg + rr];
            #pragma unroll
            for (int nt = 0; nt < 2; ++nt) {
                const u16* bp = gW3 + ((size_t)(b * 2 + nt) * 2) * 512 + l * 8;
                s8v bv0 = *(const s8v*)(bp);
                s8v bv1 = *(const s8v*)(bp + 512);
                f4v D = __builtin_amdgcn_mfma_f32_16x16x32_bf16(avI3, bv0, zf, 0, 0, 0);
                D = __builtin_amdgcn_mfma_f32_16x16x32_bf16(avJ3, bv1, D, 0, 0, 0);
                #pragma unroll
                for (int rr = 0; rr < 4; ++rr)
                    accP[nt][rr] += tb[rr] * D[rr];
            }
        }
        // ii3 + combine + atomic p3n
        #pragma unroll
        for (int nt = 0; nt < 2; ++nt)
            #pragma unroll
            for (int rr = 0; rr < 4; ++rr)
                sT2[(4 * kg + rr) * 40 + 16 * nt + r16] = (u16)f2b(accP[nt][rr]);
        s8v av = *(const s8v*)(sT2 + r16 * 40 + 8 * kg);
        #pragma unroll
        for (int nt = 0; nt < 2; ++nt) {
            s8v bv = *(const s8v*)(gII3 + (nt * 64 + l) * 8);
            f4v ja = __builtin_amdgcn_mfma_f32_16x16x32_bf16(av, bv, zf, 0, 0, 0);
            #pragma unroll
            for (int rr = 0; rr < 4; ++rr) {
                int rowD = 4 * kg + rr;
                float i3a = tanhf_fast(ja[rr] + vii3[nt]);
                float val = i3a * accT[2 + nt][rr] + sR3[d * 16 + rowD] * accT[4 + nt][rr];
                atomicAdd(&p3n[((size_t)sIdxJ[rowD] * 3 + d) * 32 + 16 * nt + r16], val);
            }
        }
    }
}

// ---------------- finalize: p1o = sum_d p3n^2 + p1n ; p3o = p3n * p1o -----
__global__ __launch_bounds__(256) void finalize_kernel(
    const float* __restrict__ p1n, const float* __restrict__ p3n,
    float* __restrict__ out)
{
    int t = blockIdx.x * 256 + threadIdx.x;
    int n = t >> 5, c = t & 31;
    float a0 = p3n[(n * 3 + 0) * 32 + c];
    float a1 = p3n[(n * 3 + 1) * 32 + c];
    float a2 = p3n[(n * 3 + 2) * 32 + c];
    float p1o = p1n[t] + a0 * a0 + a1 * a1 + a2 * a2;
    out[t] = p1o;
    float* o3 = out + NN * 32;
    o3[(n * 3 + 0) * 32 + c] = a0 * p1o;
    o3[(n * 3 + 1) * 32 + c] = a1 * p1o;
    o3[(n * 3 + 2) * 32 + c] = a2 * p1o;
}

extern "C" void kernel_launch(void* const* d_in, const int* in_sizes, int n_in,
                              void* d_out, int out_size, void* d_ws, size_t ws_size,
                              hipStream_t stream) {
    const float* p1     = (const float*)d_in[0];
    const float* p3     = (const float*)d_in[1];
    const float* r3     = (const float*)d_in[2];
    const float* basis  = (const float*)d_in[3];
    const int*   idx_i  = (const int*)d_in[4];
    const int*   idx_j  = (const int*)d_in[5];
    const float* pp1_W  = (const float*)d_in[6];
    const float* pp1_b  = (const float*)d_in[7];
    const float* pi1_W1 = (const float*)d_in[8];
    const float* pi1_b1 = (const float*)d_in[9];
    const float* pi1_W2 = (const float*)d_in[10];
    const float* pi1_b2 = (const float*)d_in[11];
    const float* pi1_W3 = (const float*)d_in[12];
    const float* ii1_W  = (const float*)d_in[13];
    const float* ii1_b  = (const float*)d_in[14];
    const float* pp3_W  = (const float*)d_in[15];
    const float* pp3_b  = (const float*)d_in[16];
    const float* pi3_W1 = (const float*)d_in[17];
    const float* pi3_b1 = (const float*)d_in[18];
    const float* pi3_W2 = (const float*)d_in[19];
    const float* pi3_b2 = (const float*)d_in[20];
    const float* pi3_W3 = (const float*)d_in[21];
    const float* ii3_W  = (const float*)d_in[22];
    const float* ii3_b  = (const float*)d_in[23];

    char* ws = (char*)d_ws;
    u16*   p1hb = (u16*)(ws + OFF_P1HB);
    u16*   p3hb = (u16*)(ws + OFF_P3HB);
    u16*   wb   = (u16*)(ws + OFF_WB);
    float* p1n  = (float*)(ws + OFF_P1N);
    float* p3n  = (float*)(ws + OFF_P3N);

    prep_kernel<<<dim3(6347), dim3(256), 0, stream>>>(
        p1, p3, pp1_W, pp1_b, pp3_W, pp3_b,
        pi1_W1, pi1_W2, pi1_W3, pi1_b1, pi1_b2, ii1_W,
        pi3_W1, pi3_W2, pi3_W3, pi3_b1, pi3_b2, ii3_W,
        p1hb, p3hb, wb, p1n);

    edge_kernel<<<dim3(NE / 16), dim3(64), 0, stream>>>(
        p1hb, p3hb, r3, basis, idx_i, idx_j, wb,
        ii1_b, ii3_b, p1n, p3n);

    finalize_kernel<<<dim3(1250), dim3(256), 0, stream>>>(p1n, p3n, (float*)d_out);
}